// Round 1
// baseline (4891.149 us; speedup 1.0000x reference)
//
#include <hip/hip_runtime.h>
#include <cstdint>

#define NB 16384   // batch
#define NM 256     // M
#define NN 1024    // N
#define NITER 16
#define TOPK 50

// ---------------- transpose phi (NM x NN) -> phiT (NN x NM) ----------------
__global__ __launch_bounds__(256) void transpose_kernel(const float* __restrict__ phi,
                                                        float* __restrict__ phiT) {
    __shared__ float tile[32][33];
    int n0 = blockIdx.x * 32;
    int m0 = blockIdx.y * 32;
    int tx = threadIdx.x;   // 0..31
    int ty = threadIdx.y;   // 0..7
    #pragma unroll
    for (int i = 0; i < 32; i += 8)
        tile[ty + i][tx] = phi[(size_t)(m0 + ty + i) * NN + n0 + tx];
    __syncthreads();
    #pragma unroll
    for (int i = 0; i < 32; i += 8)
        phiT[(size_t)(n0 + ty + i) * NM + m0 + tx] = tile[tx][ty + i];
}

// ---------------- GEMM1: Rt(NB x NM) = X(NB x NN) @ phiT(NN x NM) - y ------
__global__ __launch_bounds__(256) void gemm1_kernel(const float* __restrict__ X,
                                                    const float* __restrict__ phiT,
                                                    const float* __restrict__ y,
                                                    float* __restrict__ Rt) {
    const int BM = 128, BN = 64, BK = 16;
    __shared__ float As[BK][BM + 4];   // pad keeps 16B alignment (132*4=528)
    __shared__ float Bs[BK][BN + 4];   // 68*4=272, 16B aligned
    int tid = threadIdx.x;
    int b0 = blockIdx.x * BM;
    int n0 = blockIdx.y * BN;
    int tx = tid & 15;    // n dir, TN=4 -> 64
    int ty = tid >> 4;    // b dir, TM=8 -> 128
    float acc[8][4];
    #pragma unroll
    for (int i = 0; i < 8; i++)
        #pragma unroll
        for (int j = 0; j < 4; j++) acc[i][j] = 0.f;

    for (int k0 = 0; k0 < NN; k0 += BK) {
        #pragma unroll
        for (int s = 0; s < 2; ++s) {           // A tile: 512 float4
            int slot = tid * 2 + s;
            int r = slot >> 2;
            int c4 = slot & 3;
            float4 v = *reinterpret_cast<const float4*>(&X[(size_t)(b0 + r) * NN + k0 + c4 * 4]);
            As[c4 * 4 + 0][r] = v.x; As[c4 * 4 + 1][r] = v.y;
            As[c4 * 4 + 2][r] = v.z; As[c4 * 4 + 3][r] = v.w;
        }
        {                                        // B tile: 256 float4
            int r = tid >> 4;
            int c4 = tid & 15;
            float4 v = *reinterpret_cast<const float4*>(&phiT[(size_t)(k0 + r) * NM + n0 + c4 * 4]);
            Bs[r][c4 * 4 + 0] = v.x; Bs[r][c4 * 4 + 1] = v.y;
            Bs[r][c4 * 4 + 2] = v.z; Bs[r][c4 * 4 + 3] = v.w;
        }
        __syncthreads();
        #pragma unroll
        for (int k = 0; k < BK; ++k) {
            float4 a0 = *reinterpret_cast<const float4*>(&As[k][ty * 8]);
            float4 a1 = *reinterpret_cast<const float4*>(&As[k][ty * 8 + 4]);
            float4 b0v = *reinterpret_cast<const float4*>(&Bs[k][tx * 4]);
            float a[8] = {a0.x, a0.y, a0.z, a0.w, a1.x, a1.y, a1.z, a1.w};
            float bb[4] = {b0v.x, b0v.y, b0v.z, b0v.w};
            #pragma unroll
            for (int i = 0; i < 8; i++)
                #pragma unroll
                for (int j = 0; j < 4; j++) acc[i][j] += a[i] * bb[j];
        }
        __syncthreads();
    }
    #pragma unroll
    for (int i = 0; i < 8; i++) {
        int gb = b0 + ty * 8 + i;
        #pragma unroll
        for (int j = 0; j < 4; j++) {
            int gn = n0 + tx * 4 + j;
            Rt[(size_t)gb * NM + gn] = acc[i][j] - y[(size_t)gb * NM + gn];
        }
    }
}

// ------- GEMM2: V(NB x NN) = X - gamma[it] * (Rt(NB x NM) @ W(NM x NN)) ----
__global__ __launch_bounds__(256) void gemm2_kernel(const float* __restrict__ Rt,
                                                    const float* __restrict__ W,
                                                    const float* __restrict__ X,
                                                    const float* __restrict__ gamma,
                                                    int it,
                                                    float* __restrict__ V) {
    const int BM = 128, BN = 128, BK = 16;
    __shared__ float As[BK][BM + 4];
    __shared__ float Bs[BK][BN + 4];
    int tid = threadIdx.x;
    int b0 = blockIdx.x * BM;
    int n0 = blockIdx.y * BN;
    int tx = tid & 15;    // n dir, TN=8 -> 128
    int ty = tid >> 4;    // b dir, TM=8 -> 128
    float acc[8][8];
    #pragma unroll
    for (int i = 0; i < 8; i++)
        #pragma unroll
        for (int j = 0; j < 8; j++) acc[i][j] = 0.f;

    for (int k0 = 0; k0 < NM; k0 += BK) {
        #pragma unroll
        for (int s = 0; s < 2; ++s) {           // A tile 128x16 -> 512 float4
            int slot = tid * 2 + s;
            int r = slot >> 2;
            int c4 = slot & 3;
            float4 v = *reinterpret_cast<const float4*>(&Rt[(size_t)(b0 + r) * NM + k0 + c4 * 4]);
            As[c4 * 4 + 0][r] = v.x; As[c4 * 4 + 1][r] = v.y;
            As[c4 * 4 + 2][r] = v.z; As[c4 * 4 + 3][r] = v.w;
        }
        #pragma unroll
        for (int s = 0; s < 2; ++s) {           // B tile 16x128 -> 512 float4
            int slot = tid * 2 + s;
            int r = slot >> 5;
            int c4 = slot & 31;
            float4 v = *reinterpret_cast<const float4*>(&W[(size_t)(k0 + r) * NN + n0 + c4 * 4]);
            Bs[r][c4 * 4 + 0] = v.x; Bs[r][c4 * 4 + 1] = v.y;
            Bs[r][c4 * 4 + 2] = v.z; Bs[r][c4 * 4 + 3] = v.w;
        }
        __syncthreads();
        #pragma unroll
        for (int k = 0; k < BK; ++k) {
            float4 a0 = *reinterpret_cast<const float4*>(&As[k][ty * 8]);
            float4 a1 = *reinterpret_cast<const float4*>(&As[k][ty * 8 + 4]);
            float4 b0v = *reinterpret_cast<const float4*>(&Bs[k][tx * 8]);
            float4 b1v = *reinterpret_cast<const float4*>(&Bs[k][tx * 8 + 4]);
            float a[8] = {a0.x, a0.y, a0.z, a0.w, a1.x, a1.y, a1.z, a1.w};
            float bb[8] = {b0v.x, b0v.y, b0v.z, b0v.w, b1v.x, b1v.y, b1v.z, b1v.w};
            #pragma unroll
            for (int i = 0; i < 8; i++)
                #pragma unroll
                for (int j = 0; j < 8; j++) acc[i][j] += a[i] * bb[j];
        }
        __syncthreads();
    }
    float gm = gamma[it];
    #pragma unroll
    for (int i = 0; i < 8; i++) {
        int gb = b0 + ty * 8 + i;
        #pragma unroll
        for (int j = 0; j < 8; j++) {
            int gn = n0 + tx * 8 + j;
            size_t idx = (size_t)gb * NN + gn;
            V[idx] = X[idx] - gm * acc[i][j];
        }
    }
}

// -------- update: per batch row, exact 50th-largest |v| radix select -------
__global__ __launch_bounds__(256) void update_kernel(const float* __restrict__ V,
                                                     const float* __restrict__ Xold,
                                                     const float* __restrict__ theta,
                                                     int it,
                                                     float* __restrict__ Xnew) {
    __shared__ unsigned hist[256];
    __shared__ unsigned scan[256];
    __shared__ unsigned s_prefix;
    __shared__ int s_r;
    int b = blockIdx.x;
    int tid = threadIdx.x;
    size_t base = (size_t)b * NN;

    float v[4];
    unsigned u[4];
    #pragma unroll
    for (int j = 0; j < 4; j++) {
        v[j] = V[base + tid + 256 * j];
        u[j] = __float_as_uint(fabsf(v[j]));
    }

    unsigned prefix = 0;
    int r = TOPK;
    #pragma unroll
    for (int pass = 0; pass < 4; ++pass) {
        int shift = 24 - 8 * pass;
        hist[tid] = 0;
        __syncthreads();
        #pragma unroll
        for (int j = 0; j < 4; j++) {
            bool match = (pass == 0) || ((u[j] >> (shift + 8)) == prefix);
            if (match) atomicAdd(&hist[(u[j] >> shift) & 255u], 1u);
        }
        __syncthreads();
        // suffix sum S[d] = sum_{e>=d} hist[e]  (Hillis-Steele, 8 steps)
        unsigned sval = hist[tid];
        scan[tid] = sval;
        __syncthreads();
        #pragma unroll
        for (int off = 1; off < 256; off <<= 1) {
            unsigned add = (tid + off < 256) ? scan[tid + off] : 0u;
            __syncthreads();
            sval += add;
            scan[tid] = sval;
            __syncthreads();
        }
        unsigned Sd = scan[tid];
        unsigned Snext = (tid == 255) ? 0u : scan[tid + 1];
        if (Sd >= (unsigned)r && Snext < (unsigned)r) {
            s_prefix = (prefix << 8) | (unsigned)tid;
            s_r = r - (int)Snext;
        }
        __syncthreads();
        prefix = s_prefix;
        r = s_r;
        __syncthreads();
    }
    unsigned T = prefix;   // bit pattern of 50th largest |v| in this row

    float thv = theta[it];
    #pragma unroll
    for (int j = 0; j < 4; j++) {
        float xo = Xold[base + tid + 256 * j];
        float th = thv / (10.0f * fabsf(xo) + 1.0f);   // theta * g(|x|), EPS=0.1
        float a = fabsf(v[j]);
        float st = copysignf(fmaxf(a - th, 0.0f), v[j]);
        float outv = (u[j] > T) ? v[j] : st;
        Xnew[base + tid + 256 * j] = outv;
    }
}

__global__ void tail_kernel(float* __restrict__ out) {
    if (threadIdx.x < 32) out[(size_t)NB * NN + threadIdx.x] = 0.0f;
}

extern "C" void kernel_launch(void* const* d_in, const int* in_sizes, int n_in,
                              void* d_out, int out_size, void* d_ws, size_t ws_size,
                              hipStream_t stream) {
    const float* y     = (const float*)d_in[0];
    const float* phi   = (const float*)d_in[1];
    const float* W     = (const float*)d_in[2];
    const float* gamma = (const float*)d_in[3];
    const float* theta = (const float*)d_in[4];
    float* out = (float*)d_out;

    char* ws = (char*)d_ws;
    float* X    = (float*)ws;                                              // NB*NN
    float* Rt   = (float*)(ws + (size_t)NB * NN * 4);                      // NB*NM
    float* phiT = (float*)(ws + (size_t)NB * NN * 4 + (size_t)NB * NM * 4);// NN*NM
    float* V = out;   // reuse output buffer as V scratch (fully rewritten each iter)

    hipMemsetAsync(X, 0, (size_t)NB * NN * 4, stream);
    transpose_kernel<<<dim3(NN / 32, NM / 32), dim3(32, 8), 0, stream>>>(phi, phiT);

    for (int it = 0; it < NITER; ++it) {
        gemm1_kernel<<<dim3(NB / 128, NM / 64), 256, 0, stream>>>(X, phiT, y, Rt);
        gemm2_kernel<<<dim3(NB / 128, NN / 128), 256, 0, stream>>>(Rt, W, X, gamma, it, V);
        float* Xn = (it == NITER - 1) ? out : X;
        update_kernel<<<NB, 256, 0, stream>>>(V, X, theta, it, Xn);
    }
    tail_kernel<<<1, 32, 0, stream>>>(out);
}

// Round 2
// 2697.422 us; speedup vs baseline: 1.8133x; 1.8133x over previous
//
#include <hip/hip_runtime.h>
#include <hip/hip_bf16.h>
#include <cstdint>

#define NB 16384   // batch
#define NM 256     // M
#define NN 1024    // N
#define NITER 16
#define TOPK 50

typedef __attribute__((ext_vector_type(8))) short short8;   // 8 bf16 = 4 VGPRs
typedef __attribute__((ext_vector_type(4))) float f32x4;

__device__ inline unsigned short f2bf(float x) {            // RNE fp32 -> bf16
    unsigned u = __float_as_uint(x);
    return (unsigned short)((u + 0x7FFFu + ((u >> 16) & 1u)) >> 16);
}
__device__ inline float bf2f(unsigned short h) {
    return __uint_as_float(((unsigned)h) << 16);
}
__device__ inline void gload16(const void* g, void* lds) {  // 16B global -> LDS
    __builtin_amdgcn_global_load_lds(
        (const __attribute__((address_space(1))) unsigned*)g,
        (__attribute__((address_space(3))) unsigned*)lds, 16, 0, 0);
}

// ------------- precompute: element-wise split of phi (NM x NN) -------------
__global__ __launch_bounds__(256) void split_phi_kernel(const float* __restrict__ phi,
                                                        unsigned short* __restrict__ h,
                                                        unsigned short* __restrict__ l) {
    int i = blockIdx.x * 256 + threadIdx.x;
    float v = phi[i];
    unsigned short hh = f2bf(v);
    h[i] = hh;
    l[i] = f2bf(v - bf2f(hh));
}

// -------- precompute: W (NM x NN) -> Wt (NN x NM) transposed + split -------
__global__ __launch_bounds__(256) void transpose_split_W(const float* __restrict__ W,
                                                         unsigned short* __restrict__ th,
                                                         unsigned short* __restrict__ tl) {
    __shared__ float tile[32][33];
    int n0 = blockIdx.x * 32;
    int m0 = blockIdx.y * 32;
    int tx = threadIdx.x;   // 0..31
    int ty = threadIdx.y;   // 0..7
    #pragma unroll
    for (int i = 0; i < 32; i += 8)
        tile[ty + i][tx] = W[(size_t)(m0 + ty + i) * NN + n0 + tx];
    __syncthreads();
    #pragma unroll
    for (int i = 0; i < 32; i += 8) {
        float v = tile[tx][ty + i];
        unsigned short hh = f2bf(v);
        size_t idx = (size_t)(n0 + ty + i) * NM + m0 + tx;
        th[idx] = hh;
        tl[idx] = f2bf(v - bf2f(hh));
    }
}

// ---- GEMM1 (MFMA): Rt(B x NM) = X(B x NN) @ phiT - y, split output ----
// A = X splits (row-major, B x NN). B-operand = phiT (NN x NM); LDS wants
// [n][k] layout == phi's native (NM x NN) layout, so stage phi splits direct.
#define BM1 128
#define BN1 64
#define BK  32
__global__ __launch_bounds__(256) void gemm1_mfma(const unsigned short* __restrict__ Xh,
                                                  const unsigned short* __restrict__ Xl,
                                                  const unsigned short* __restrict__ Ph,
                                                  const unsigned short* __restrict__ Pl,
                                                  const float* __restrict__ y,
                                                  unsigned short* __restrict__ Rth,
                                                  unsigned short* __restrict__ Rtl) {
    __shared__ unsigned short sAh[BM1 * BK];  // 8KB, row stride 32 elem = 64B
    __shared__ unsigned short sAl[BM1 * BK];
    __shared__ unsigned short sBh[BN1 * BK];  // 4KB
    __shared__ unsigned short sBl[BN1 * BK];

    const int tid = threadIdx.x, wave = tid >> 6, lane = tid & 63;
    const int b0 = blockIdx.x * BM1, n0 = blockIdx.y * BN1;
    const int wm = (wave & 1) * 64, wn = (wave >> 1) * 32;
    const int row16 = lane & 15, quad = lane >> 4;

    f32x4 acc[4][2];
    #pragma unroll
    for (int i = 0; i < 4; i++)
        #pragma unroll
        for (int j = 0; j < 2; j++) acc[i][j] = (f32x4){0.f, 0.f, 0.f, 0.f};

    for (int k0 = 0; k0 < NN; k0 += BK) {
        #pragma unroll
        for (int c = 0; c < 2; ++c) {          // A tiles: 8 chunks of 1KB
            int o = (wave * 2 + c) * 1024 + lane * 16;   // byte offset in tile
            int row = o >> 6, colb = o & 63;
            size_t g = (size_t)(b0 + row) * NN + k0 + (colb >> 1);
            gload16(&Xh[g], (char*)sAh + o);
            gload16(&Xl[g], (char*)sAl + o);
        }
        {                                       // B tiles: 4 chunks of 1KB
            int o = wave * 1024 + lane * 16;
            int nrow = o >> 6, colb = o & 63;
            size_t g = (size_t)(n0 + nrow) * NN + k0 + (colb >> 1);
            gload16(&Ph[g], (char*)sBh + o);
            gload16(&Pl[g], (char*)sBl + o);
        }
        __syncthreads();
        short8 a[4], bh[2], bl[2];
        #pragma unroll
        for (int j = 0; j < 2; ++j) {
            int off = (wn + j * 16 + row16) * 64 + quad * 16;
            bh[j] = *(const short8*)((const char*)sBh + off);
            bl[j] = *(const short8*)((const char*)sBl + off);
        }
        #pragma unroll
        for (int i = 0; i < 4; ++i)
            a[i] = *(const short8*)((const char*)sAh + (wm + i * 16 + row16) * 64 + quad * 16);
        #pragma unroll
        for (int i = 0; i < 4; ++i)
            #pragma unroll
            for (int j = 0; j < 2; ++j) {
                acc[i][j] = __builtin_amdgcn_mfma_f32_16x16x32_bf16(a[i], bh[j], acc[i][j], 0, 0, 0);
                acc[i][j] = __builtin_amdgcn_mfma_f32_16x16x32_bf16(a[i], bl[j], acc[i][j], 0, 0, 0);
            }
        #pragma unroll
        for (int i = 0; i < 4; ++i)
            a[i] = *(const short8*)((const char*)sAl + (wm + i * 16 + row16) * 64 + quad * 16);
        #pragma unroll
        for (int i = 0; i < 4; ++i)
            #pragma unroll
            for (int j = 0; j < 2; ++j)
                acc[i][j] = __builtin_amdgcn_mfma_f32_16x16x32_bf16(a[i], bh[j], acc[i][j], 0, 0, 0);
        __syncthreads();
    }
    #pragma unroll
    for (int i = 0; i < 4; ++i)
        #pragma unroll
        for (int j = 0; j < 2; ++j)
            #pragma unroll
            for (int r = 0; r < 4; ++r) {
                int gm = b0 + wm + i * 16 + quad * 4 + r;
                int gn = n0 + wn + j * 16 + row16;
                size_t idx = (size_t)gm * NM + gn;
                float v = acc[i][j][r] - y[idx];
                unsigned short h = f2bf(v);
                Rth[idx] = h;
                Rtl[idx] = f2bf(v - bf2f(h));
            }
}

// ---- GEMM2 (MFMA): V(B x NN) = X - gamma * (Rt(B x NM) @ W(NM x NN)) ----
#define BM2 128
#define BN2 128
__global__ __launch_bounds__(256) void gemm2_mfma(const unsigned short* __restrict__ Rth,
                                                  const unsigned short* __restrict__ Rtl,
                                                  const unsigned short* __restrict__ Wth,
                                                  const unsigned short* __restrict__ Wtl,
                                                  const unsigned short* __restrict__ Xh,
                                                  const unsigned short* __restrict__ Xl,
                                                  const float* __restrict__ gamma,
                                                  int it,
                                                  float* __restrict__ V) {
    __shared__ unsigned short sAh[BM2 * BK];  // 8KB each
    __shared__ unsigned short sAl[BM2 * BK];
    __shared__ unsigned short sBh[BN2 * BK];
    __shared__ unsigned short sBl[BN2 * BK];

    const int tid = threadIdx.x, wave = tid >> 6, lane = tid & 63;
    const int b0 = blockIdx.x * BM2, n0 = blockIdx.y * BN2;
    const int wm = (wave & 1) * 64, wn = (wave >> 1) * 64;
    const int row16 = lane & 15, quad = lane >> 4;

    f32x4 acc[4][4];
    #pragma unroll
    for (int i = 0; i < 4; i++)
        #pragma unroll
        for (int j = 0; j < 4; j++) acc[i][j] = (f32x4){0.f, 0.f, 0.f, 0.f};

    for (int k0 = 0; k0 < NM; k0 += BK) {
        #pragma unroll
        for (int c = 0; c < 2; ++c) {
            int o = (wave * 2 + c) * 1024 + lane * 16;
            int row = o >> 6, colb = o & 63;
            size_t gA = (size_t)(b0 + row) * NM + k0 + (colb >> 1);
            gload16(&Rth[gA], (char*)sAh + o);
            gload16(&Rtl[gA], (char*)sAl + o);
            size_t gB = (size_t)(n0 + row) * NM + k0 + (colb >> 1);
            gload16(&Wth[gB], (char*)sBh + o);
            gload16(&Wtl[gB], (char*)sBl + o);
        }
        __syncthreads();
        short8 a[4], bh[4], bl[4];
        #pragma unroll
        for (int j = 0; j < 4; ++j) {
            int off = (wn + j * 16 + row16) * 64 + quad * 16;
            bh[j] = *(const short8*)((const char*)sBh + off);
            bl[j] = *(const short8*)((const char*)sBl + off);
        }
        #pragma unroll
        for (int i = 0; i < 4; ++i)
            a[i] = *(const short8*)((const char*)sAh + (wm + i * 16 + row16) * 64 + quad * 16);
        #pragma unroll
        for (int i = 0; i < 4; ++i)
            #pragma unroll
            for (int j = 0; j < 4; ++j) {
                acc[i][j] = __builtin_amdgcn_mfma_f32_16x16x32_bf16(a[i], bh[j], acc[i][j], 0, 0, 0);
                acc[i][j] = __builtin_amdgcn_mfma_f32_16x16x32_bf16(a[i], bl[j], acc[i][j], 0, 0, 0);
            }
        #pragma unroll
        for (int i = 0; i < 4; ++i)
            a[i] = *(const short8*)((const char*)sAl + (wm + i * 16 + row16) * 64 + quad * 16);
        #pragma unroll
        for (int i = 0; i < 4; ++i)
            #pragma unroll
            for (int j = 0; j < 4; ++j)
                acc[i][j] = __builtin_amdgcn_mfma_f32_16x16x32_bf16(a[i], bh[j], acc[i][j], 0, 0, 0);
        __syncthreads();
    }
    float gm = gamma[it];
    #pragma unroll
    for (int i = 0; i < 4; ++i)
        #pragma unroll
        for (int j = 0; j < 4; ++j)
            #pragma unroll
            for (int r = 0; r < 4; ++r) {
                int gmr = b0 + wm + i * 16 + quad * 4 + r;
                int gn = n0 + wn + j * 16 + row16;
                size_t idx = (size_t)gmr * NN + gn;
                float xo = bf2f(Xh[idx]) + bf2f(Xl[idx]);
                V[idx] = xo - gm * acc[i][j][r];
            }
}

// -------- update: exact 50th-largest |v| radix select + soft-threshold -----
__global__ __launch_bounds__(256) void update_kernel(const float* __restrict__ V,
                                                     unsigned short* __restrict__ Xh,
                                                     unsigned short* __restrict__ Xl,
                                                     const float* __restrict__ theta,
                                                     int it,
                                                     float* __restrict__ out) {
    __shared__ unsigned hist[256];
    __shared__ unsigned scan[256];
    __shared__ unsigned s_prefix;
    __shared__ int s_r;
    int b = blockIdx.x;
    int tid = threadIdx.x;
    size_t base = (size_t)b * NN;

    float v[4];
    unsigned u[4];
    #pragma unroll
    for (int j = 0; j < 4; j++) {
        v[j] = V[base + tid + 256 * j];
        u[j] = __float_as_uint(fabsf(v[j]));
    }

    unsigned prefix = 0;
    int r = TOPK;
    #pragma unroll
    for (int pass = 0; pass < 4; ++pass) {
        int shift = 24 - 8 * pass;
        hist[tid] = 0;
        __syncthreads();
        #pragma unroll
        for (int j = 0; j < 4; j++) {
            bool match = (pass == 0) || ((u[j] >> (shift + 8)) == prefix);
            if (match) atomicAdd(&hist[(u[j] >> shift) & 255u], 1u);
        }
        __syncthreads();
        unsigned sval = hist[tid];
        scan[tid] = sval;
        __syncthreads();
        #pragma unroll
        for (int off = 1; off < 256; off <<= 1) {
            unsigned add = (tid + off < 256) ? scan[tid + off] : 0u;
            __syncthreads();
            sval += add;
            scan[tid] = sval;
            __syncthreads();
        }
        unsigned Sd = scan[tid];
        unsigned Snext = (tid == 255) ? 0u : scan[tid + 1];
        if (Sd >= (unsigned)r && Snext < (unsigned)r) {
            s_prefix = (prefix << 8) | (unsigned)tid;
            s_r = r - (int)Snext;
        }
        __syncthreads();
        prefix = s_prefix;
        r = s_r;
        __syncthreads();
    }
    unsigned T = prefix;

    float thv = theta[it];
    #pragma unroll
    for (int j = 0; j < 4; j++) {
        size_t idx = base + tid + 256 * j;
        float xo = bf2f(Xh[idx]) + bf2f(Xl[idx]);
        float th = thv / (10.0f * fabsf(xo) + 1.0f);   // theta * g(|x|), EPS=0.1
        float a = fabsf(v[j]);
        float st = copysignf(fmaxf(a - th, 0.0f), v[j]);
        float outv = (u[j] > T) ? v[j] : st;
        unsigned short h = f2bf(outv);
        Xh[idx] = h;
        Xl[idx] = f2bf(outv - bf2f(h));
        if (it == NITER - 1) out[idx] = outv;
    }
}

__global__ void tail_kernel(float* __restrict__ out) {
    if (threadIdx.x < 32) out[(size_t)NB * NN + threadIdx.x] = 0.0f;
}

extern "C" void kernel_launch(void* const* d_in, const int* in_sizes, int n_in,
                              void* d_out, int out_size, void* d_ws, size_t ws_size,
                              hipStream_t stream) {
    const float* y     = (const float*)d_in[0];
    const float* phi   = (const float*)d_in[1];
    const float* W     = (const float*)d_in[2];
    const float* gamma = (const float*)d_in[3];
    const float* theta = (const float*)d_in[4];
    float* out = (float*)d_out;

    char* ws = (char*)d_ws;
    size_t off = 0;
    unsigned short* Xh  = (unsigned short*)(ws + off); off += (size_t)NB * NN * 2;  // 32MB
    unsigned short* Xl  = (unsigned short*)(ws + off); off += (size_t)NB * NN * 2;  // 32MB
    unsigned short* Rth = (unsigned short*)(ws + off); off += (size_t)NB * NM * 2;  // 8MB
    unsigned short* Rtl = (unsigned short*)(ws + off); off += (size_t)NB * NM * 2;  // 8MB
    unsigned short* Ph  = (unsigned short*)(ws + off); off += (size_t)NM * NN * 2;  // 512KB
    unsigned short* Pl  = (unsigned short*)(ws + off); off += (size_t)NM * NN * 2;
    unsigned short* Wth = (unsigned short*)(ws + off); off += (size_t)NN * NM * 2;
    unsigned short* Wtl = (unsigned short*)(ws + off); off += (size_t)NN * NM * 2;
    float* V = out;   // V scratch aliases output (fully rewritten each iter)

    hipMemsetAsync(Xh, 0, (size_t)NB * NN * 2, stream);
    hipMemsetAsync(Xl, 0, (size_t)NB * NN * 2, stream);
    split_phi_kernel<<<(NM * NN) / 256, 256, 0, stream>>>(phi, Ph, Pl);
    transpose_split_W<<<dim3(NN / 32, NM / 32), dim3(32, 8), 0, stream>>>(W, Wth, Wtl);

    for (int it = 0; it < NITER; ++it) {
        gemm1_mfma<<<dim3(NB / BM1, NM / BN1), 256, 0, stream>>>(Xh, Xl, Ph, Pl, y, Rth, Rtl);
        gemm2_mfma<<<dim3(NB / BM2, NN / BN2), 256, 0, stream>>>(Rth, Rtl, Wth, Wtl, Xh, Xl,
                                                                 gamma, it, V);
        update_kernel<<<NB, 256, 0, stream>>>(V, Xh, Xl, theta, it, out);
    }
    tail_kernel<<<1, 32, 0, stream>>>(out);
}

// Round 3
// 2023.965 us; speedup vs baseline: 2.4166x; 1.3327x over previous
//
#include <hip/hip_runtime.h>
#include <hip/hip_bf16.h>
#include <cstdint>

#define NB 16384   // batch
#define NM 256     // M
#define NN 1024    // N
#define NITER 16
#define TOPK 50

typedef __attribute__((ext_vector_type(8))) short short8;   // 8 bf16 = 4 VGPRs
typedef __attribute__((ext_vector_type(4))) float f32x4;

__device__ inline unsigned short f2bf(float x) {            // RNE fp32 -> bf16
    unsigned u = __float_as_uint(x);
    return (unsigned short)((u + 0x7FFFu + ((u >> 16) & 1u)) >> 16);
}
__device__ inline float bf2f(unsigned short h) {
    return __uint_as_float(((unsigned)h) << 16);
}
__device__ inline void gload16(const void* g, void* lds) {  // 16B global -> LDS
    __builtin_amdgcn_global_load_lds(
        (const __attribute__((address_space(1))) unsigned*)g,
        (__attribute__((address_space(3))) unsigned*)lds, 16, 0, 0);
}

// ------------- precompute: element-wise split of phi (NM x NN) -------------
__global__ __launch_bounds__(256) void split_phi_kernel(const float* __restrict__ phi,
                                                        unsigned short* __restrict__ h,
                                                        unsigned short* __restrict__ l) {
    int i = blockIdx.x * 256 + threadIdx.x;
    float v = phi[i];
    unsigned short hh = f2bf(v);
    h[i] = hh;
    l[i] = f2bf(v - bf2f(hh));
}

// -------- precompute: W (NM x NN) -> Wt (NN x NM) transposed + split -------
__global__ __launch_bounds__(256) void transpose_split_W(const float* __restrict__ W,
                                                         unsigned short* __restrict__ th,
                                                         unsigned short* __restrict__ tl) {
    __shared__ float tile[32][33];
    int n0 = blockIdx.x * 32;
    int m0 = blockIdx.y * 32;
    int tx = threadIdx.x;   // 0..31
    int ty = threadIdx.y;   // 0..7
    #pragma unroll
    for (int i = 0; i < 32; i += 8)
        tile[ty + i][tx] = W[(size_t)(m0 + ty + i) * NN + n0 + tx];
    __syncthreads();
    #pragma unroll
    for (int i = 0; i < 32; i += 8) {
        float v = tile[tx][ty + i];
        unsigned short hh = f2bf(v);
        size_t idx = (size_t)(n0 + ty + i) * NM + m0 + tx;
        th[idx] = hh;
        tl[idx] = f2bf(v - bf2f(hh));
    }
}

// ---- GEMM1 (MFMA): Rt(B x NM) = X(B x NN) @ phiT - y, split output ----
#define BM1 128
#define BN1 64
#define BK  32
__global__ __launch_bounds__(256) void gemm1_mfma(const unsigned short* __restrict__ Xh,
                                                  const unsigned short* __restrict__ Xl,
                                                  const unsigned short* __restrict__ Ph,
                                                  const unsigned short* __restrict__ Pl,
                                                  const float* __restrict__ y,
                                                  unsigned short* __restrict__ Rth,
                                                  unsigned short* __restrict__ Rtl) {
    __shared__ unsigned short sAh[BM1 * BK];  // 8KB, row stride 32 elem = 64B
    __shared__ unsigned short sAl[BM1 * BK];
    __shared__ unsigned short sBh[BN1 * BK];  // 4KB
    __shared__ unsigned short sBl[BN1 * BK];

    const int tid = threadIdx.x, wave = tid >> 6, lane = tid & 63;
    const int b0 = blockIdx.x * BM1, n0 = blockIdx.y * BN1;
    const int wm = (wave & 1) * 64, wn = (wave >> 1) * 32;
    const int row16 = lane & 15, quad = lane >> 4;

    f32x4 acc[4][2];
    #pragma unroll
    for (int i = 0; i < 4; i++)
        #pragma unroll
        for (int j = 0; j < 2; j++) acc[i][j] = (f32x4){0.f, 0.f, 0.f, 0.f};

    for (int k0 = 0; k0 < NN; k0 += BK) {
        #pragma unroll
        for (int c = 0; c < 2; ++c) {          // A tiles: 8 chunks of 1KB
            int o = (wave * 2 + c) * 1024 + lane * 16;   // byte offset in tile
            int row = o >> 6, colb = o & 63;
            size_t g = (size_t)(b0 + row) * NN + k0 + (colb >> 1);
            gload16(&Xh[g], (char*)sAh + o);
            gload16(&Xl[g], (char*)sAl + o);
        }
        {                                       // B tiles: 4 chunks of 1KB
            int o = wave * 1024 + lane * 16;
            int nrow = o >> 6, colb = o & 63;
            size_t g = (size_t)(n0 + nrow) * NN + k0 + (colb >> 1);
            gload16(&Ph[g], (char*)sBh + o);
            gload16(&Pl[g], (char*)sBl + o);
        }
        __syncthreads();
        short8 a[4], bh[2], bl[2];
        #pragma unroll
        for (int j = 0; j < 2; ++j) {
            int off = (wn + j * 16 + row16) * 64 + quad * 16;
            bh[j] = *(const short8*)((const char*)sBh + off);
            bl[j] = *(const short8*)((const char*)sBl + off);
        }
        #pragma unroll
        for (int i = 0; i < 4; ++i)
            a[i] = *(const short8*)((const char*)sAh + (wm + i * 16 + row16) * 64 + quad * 16);
        #pragma unroll
        for (int i = 0; i < 4; ++i)
            #pragma unroll
            for (int j = 0; j < 2; ++j) {
                acc[i][j] = __builtin_amdgcn_mfma_f32_16x16x32_bf16(a[i], bh[j], acc[i][j], 0, 0, 0);
                acc[i][j] = __builtin_amdgcn_mfma_f32_16x16x32_bf16(a[i], bl[j], acc[i][j], 0, 0, 0);
            }
        #pragma unroll
        for (int i = 0; i < 4; ++i)
            a[i] = *(const short8*)((const char*)sAl + (wm + i * 16 + row16) * 64 + quad * 16);
        #pragma unroll
        for (int i = 0; i < 4; ++i)
            #pragma unroll
            for (int j = 0; j < 2; ++j)
                acc[i][j] = __builtin_amdgcn_mfma_f32_16x16x32_bf16(a[i], bh[j], acc[i][j], 0, 0, 0);
        __syncthreads();
    }
    #pragma unroll
    for (int i = 0; i < 4; ++i)
        #pragma unroll
        for (int j = 0; j < 2; ++j)
            #pragma unroll
            for (int r = 0; r < 4; ++r) {
                int gm = b0 + wm + i * 16 + quad * 4 + r;
                int gn = n0 + wn + j * 16 + row16;
                size_t idx = (size_t)gm * NM + gn;
                float v = acc[i][j][r] - y[idx];
                unsigned short h = f2bf(v);
                Rth[idx] = h;
                Rtl[idx] = f2bf(v - bf2f(h));
            }
}

// ---- GEMM2 (MFMA): V(B x NN) = X - gamma * (Rt(B x NM) @ W(NM x NN)) ----
#define BM2 128
#define BN2 128
__global__ __launch_bounds__(256) void gemm2_mfma(const unsigned short* __restrict__ Rth,
                                                  const unsigned short* __restrict__ Rtl,
                                                  const unsigned short* __restrict__ Wth,
                                                  const unsigned short* __restrict__ Wtl,
                                                  const unsigned short* __restrict__ Xh,
                                                  const unsigned short* __restrict__ Xl,
                                                  const float* __restrict__ gamma,
                                                  int it,
                                                  float* __restrict__ V) {
    __shared__ unsigned short sAh[BM2 * BK];  // 8KB each
    __shared__ unsigned short sAl[BM2 * BK];
    __shared__ unsigned short sBh[BN2 * BK];
    __shared__ unsigned short sBl[BN2 * BK];

    const int tid = threadIdx.x, wave = tid >> 6, lane = tid & 63;
    const int b0 = blockIdx.x * BM2, n0 = blockIdx.y * BN2;
    const int wm = (wave & 1) * 64, wn = (wave >> 1) * 64;
    const int row16 = lane & 15, quad = lane >> 4;

    f32x4 acc[4][4];
    #pragma unroll
    for (int i = 0; i < 4; i++)
        #pragma unroll
        for (int j = 0; j < 4; j++) acc[i][j] = (f32x4){0.f, 0.f, 0.f, 0.f};

    for (int k0 = 0; k0 < NM; k0 += BK) {
        #pragma unroll
        for (int c = 0; c < 2; ++c) {
            int o = (wave * 2 + c) * 1024 + lane * 16;
            int row = o >> 6, colb = o & 63;
            size_t gA = (size_t)(b0 + row) * NM + k0 + (colb >> 1);
            gload16(&Rth[gA], (char*)sAh + o);
            gload16(&Rtl[gA], (char*)sAl + o);
            size_t gB = (size_t)(n0 + row) * NM + k0 + (colb >> 1);
            gload16(&Wth[gB], (char*)sBh + o);
            gload16(&Wtl[gB], (char*)sBl + o);
        }
        __syncthreads();
        short8 a[4], bh[4], bl[4];
        #pragma unroll
        for (int j = 0; j < 4; ++j) {
            int off = (wn + j * 16 + row16) * 64 + quad * 16;
            bh[j] = *(const short8*)((const char*)sBh + off);
            bl[j] = *(const short8*)((const char*)sBl + off);
        }
        #pragma unroll
        for (int i = 0; i < 4; ++i)
            a[i] = *(const short8*)((const char*)sAh + (wm + i * 16 + row16) * 64 + quad * 16);
        #pragma unroll
        for (int i = 0; i < 4; ++i)
            #pragma unroll
            for (int j = 0; j < 4; ++j) {
                acc[i][j] = __builtin_amdgcn_mfma_f32_16x16x32_bf16(a[i], bh[j], acc[i][j], 0, 0, 0);
                acc[i][j] = __builtin_amdgcn_mfma_f32_16x16x32_bf16(a[i], bl[j], acc[i][j], 0, 0, 0);
            }
        #pragma unroll
        for (int i = 0; i < 4; ++i)
            a[i] = *(const short8*)((const char*)sAl + (wm + i * 16 + row16) * 64 + quad * 16);
        #pragma unroll
        for (int i = 0; i < 4; ++i)
            #pragma unroll
            for (int j = 0; j < 4; ++j)
                acc[i][j] = __builtin_amdgcn_mfma_f32_16x16x32_bf16(a[i], bh[j], acc[i][j], 0, 0, 0);
        __syncthreads();
    }
    float gm = gamma[it];
    #pragma unroll
    for (int i = 0; i < 4; ++i)
        #pragma unroll
        for (int j = 0; j < 4; ++j)
            #pragma unroll
            for (int r = 0; r < 4; ++r) {
                int gmr = b0 + wm + i * 16 + quad * 4 + r;
                int gn = n0 + wn + j * 16 + row16;
                size_t idx = (size_t)gmr * NN + gn;
                float xo = bf2f(Xh[idx]) + bf2f(Xl[idx]);
                V[idx] = xo - gm * acc[i][j][r];
            }
}

// -------- update: exact 50th-largest |v| via single-pass 2048-bin select ---
// bits [30:20] histogram (sign always 0 for |v|), hierarchical suffix scan,
// then exact rank-count refinement of the low 20 bits among matching elems.
// Produces the identical threshold bit pattern T as a full radix select.
__global__ __launch_bounds__(256) void update_kernel(const float* __restrict__ V,
                                                     unsigned short* __restrict__ Xh,
                                                     unsigned short* __restrict__ Xl,
                                                     const float* __restrict__ theta,
                                                     int it,
                                                     float* __restrict__ out) {
    __shared__ unsigned hist[2048];    // 8KB
    __shared__ unsigned wtot[4];
    __shared__ unsigned s_bin;
    __shared__ unsigned s_r2;
    __shared__ unsigned s_cnt;
    __shared__ unsigned s_T;
    __shared__ unsigned s_low[1024];   // 4KB worst case

    const int b = blockIdx.x, tid = threadIdx.x;
    const int lane = tid & 63, wave = tid >> 6;
    const size_t base = (size_t)b * NN + tid * 4;

    float4 vv = *reinterpret_cast<const float4*>(&V[base]);
    float v[4] = {vv.x, vv.y, vv.z, vv.w};
    unsigned u[4];
    #pragma unroll
    for (int j = 0; j < 4; j++) u[j] = __float_as_uint(fabsf(v[j]));

    // clear
    uint4 z4 = {0u, 0u, 0u, 0u};
    reinterpret_cast<uint4*>(hist)[tid] = z4;
    reinterpret_cast<uint4*>(hist)[tid + 256] = z4;
    if (tid == 0) s_cnt = 0;
    __syncthreads();

    #pragma unroll
    for (int j = 0; j < 4; j++) atomicAdd(&hist[u[j] >> 20], 1u);
    __syncthreads();

    // thread t owns bins [t*8, t*8+8)
    unsigned loc[8];
    uint4 h0 = reinterpret_cast<const uint4*>(hist)[tid * 2];
    uint4 h1 = reinterpret_cast<const uint4*>(hist)[tid * 2 + 1];
    loc[0] = h0.x; loc[1] = h0.y; loc[2] = h0.z; loc[3] = h0.w;
    loc[4] = h1.x; loc[5] = h1.y; loc[6] = h1.z; loc[7] = h1.w;
    unsigned lsum = 0;
    #pragma unroll
    for (int i = 0; i < 8; i++) lsum += loc[i];

    // wave-level inclusive suffix scan of lsum (no LDS, no barriers)
    unsigned s = lsum;
    #pragma unroll
    for (int off = 1; off < 64; off <<= 1) {
        unsigned o = __shfl_down(s, off, 64);
        if (lane + off < 64) s += o;
    }
    if (lane == 0) wtot[wave] = s;   // wave total
    __syncthreads();
    unsigned after_wave = 0;
    #pragma unroll
    for (int w = 0; w < 4; ++w)
        if (w > wave) after_wave += wtot[w];
    unsigned S_incl = s + after_wave;      // suffix incl. this thread's bins
    unsigned run = S_incl - lsum;          // suffix of all higher bins

    const unsigned r = TOPK;
    #pragma unroll
    for (int i = 7; i >= 0; --i) {         // high bin = larger value
        unsigned sufThis = run + loc[i];
        if (sufThis >= r && run < r) { s_bin = tid * 8 + i; s_r2 = r - run; }
        run = sufThis;
    }
    __syncthreads();
    const unsigned bin = s_bin, r2 = s_r2;

    // collect low-20-bit remainders of prefix-matching elements
    #pragma unroll
    for (int j = 0; j < 4; j++) {
        if ((u[j] >> 20) == bin) {
            unsigned p = atomicAdd(&s_cnt, 1u);
            s_low[p] = u[j] & 0xFFFFFu;
        }
    }
    __syncthreads();
    const unsigned c = s_cnt;
    for (unsigned p = tid; p < c; p += 256) {
        unsigned x = s_low[p];
        unsigned cg = 0, ce = 0;
        for (unsigned q = 0; q < c; ++q) {
            unsigned yq = s_low[q];
            cg += (yq > x);
            ce += (yq == x);
        }
        if (cg < r2 && cg + ce >= r2) s_T = (bin << 20) | x;
    }
    __syncthreads();
    const unsigned T = s_T;   // exact bit pattern of 50th-largest |v|

    // epilogue: soft-threshold + exact top-k passthrough, split-write X
    float thv = theta[it];
    ushort4 xh4 = *reinterpret_cast<const ushort4*>(&Xh[base]);
    ushort4 xl4 = *reinterpret_cast<const ushort4*>(&Xl[base]);
    const unsigned short* xhp = reinterpret_cast<const unsigned short*>(&xh4);
    const unsigned short* xlp = reinterpret_cast<const unsigned short*>(&xl4);
    ushort4 nh4, nl4;
    unsigned short* nhp = reinterpret_cast<unsigned short*>(&nh4);
    unsigned short* nlp = reinterpret_cast<unsigned short*>(&nl4);
    float ov[4];
    #pragma unroll
    for (int j = 0; j < 4; j++) {
        float xo = bf2f(xhp[j]) + bf2f(xlp[j]);
        float th = thv / (10.0f * fabsf(xo) + 1.0f);   // theta * g(|x|), EPS=0.1
        float a = fabsf(v[j]);
        float st = copysignf(fmaxf(a - th, 0.0f), v[j]);
        float outv = (u[j] > T) ? v[j] : st;
        unsigned short h = f2bf(outv);
        nhp[j] = h;
        nlp[j] = f2bf(outv - bf2f(h));
        ov[j] = outv;
    }
    *reinterpret_cast<ushort4*>(&Xh[base]) = nh4;
    *reinterpret_cast<ushort4*>(&Xl[base]) = nl4;
    if (it == NITER - 1)
        *reinterpret_cast<float4*>(&out[base]) = *reinterpret_cast<float4*>(ov);
}

__global__ void tail_kernel(float* __restrict__ out) {
    if (threadIdx.x < 32) out[(size_t)NB * NN + threadIdx.x] = 0.0f;
}

extern "C" void kernel_launch(void* const* d_in, const int* in_sizes, int n_in,
                              void* d_out, int out_size, void* d_ws, size_t ws_size,
                              hipStream_t stream) {
    const float* y     = (const float*)d_in[0];
    const float* phi   = (const float*)d_in[1];
    const float* W     = (const float*)d_in[2];
    const float* gamma = (const float*)d_in[3];
    const float* theta = (const float*)d_in[4];
    float* out = (float*)d_out;

    char* ws = (char*)d_ws;
    size_t off = 0;
    unsigned short* Xh  = (unsigned short*)(ws + off); off += (size_t)NB * NN * 2;  // 32MB
    unsigned short* Xl  = (unsigned short*)(ws + off); off += (size_t)NB * NN * 2;  // 32MB
    unsigned short* Rth = (unsigned short*)(ws + off); off += (size_t)NB * NM * 2;  // 8MB
    unsigned short* Rtl = (unsigned short*)(ws + off); off += (size_t)NB * NM * 2;  // 8MB
    unsigned short* Ph  = (unsigned short*)(ws + off); off += (size_t)NM * NN * 2;  // 512KB
    unsigned short* Pl  = (unsigned short*)(ws + off); off += (size_t)NM * NN * 2;
    unsigned short* Wth = (unsigned short*)(ws + off); off += (size_t)NN * NM * 2;
    unsigned short* Wtl = (unsigned short*)(ws + off); off += (size_t)NN * NM * 2;
    float* V = out;   // V scratch aliases output (fully rewritten each iter)

    hipMemsetAsync(Xh, 0, (size_t)NB * NN * 2, stream);
    hipMemsetAsync(Xl, 0, (size_t)NB * NN * 2, stream);
    split_phi_kernel<<<(NM * NN) / 256, 256, 0, stream>>>(phi, Ph, Pl);
    transpose_split_W<<<dim3(NN / 32, NM / 32), dim3(32, 8), 0, stream>>>(W, Wth, Wtl);

    for (int it = 0; it < NITER; ++it) {
        gemm1_mfma<<<dim3(NB / BM1, NM / BN1), 256, 0, stream>>>(Xh, Xl, Ph, Pl, y, Rth, Rtl);
        gemm2_mfma<<<dim3(NB / BM2, NN / BN2), 256, 0, stream>>>(Rth, Rtl, Wth, Wtl, Xh, Xl,
                                                                 gamma, it, V);
        update_kernel<<<NB, 256, 0, stream>>>(V, Xh, Xl, theta, it, out);
    }
    tail_kernel<<<1, 32, 0, stream>>>(out);
}